// Round 4
// baseline (369.526 us; speedup 1.0000x reference)
//
#include <hip/hip_runtime.h>
#include <math.h>

#define S_LEN 4096
#define DMODEL 2048
#define NH 16
#define NKVH 4
#define HD 128
#define LDQKV 3072   // NH*HD + 2*NKVH*HD

typedef __attribute__((ext_vector_type(4))) float f32x4;
typedef __attribute__((ext_vector_type(8))) short bf16x8;
typedef __attribute__((ext_vector_type(4))) unsigned short us4;

static __device__ __forceinline__ unsigned short f2bf(float f) {
  unsigned int u = __builtin_bit_cast(unsigned int, f);
  u += 0x7fffu + ((u >> 16) & 1u);
  return (unsigned short)(u >> 16);
}
static __device__ __forceinline__ float bf2f(unsigned short h) {
  unsigned int u = ((unsigned int)h) << 16;
  return __builtin_bit_cast(float, u);
}
static __device__ __forceinline__ unsigned int cvt_pk_bf16(float lo, float hi) {
  unsigned int r;
  asm("v_cvt_pk_bf16_f32 %0, %1, %2" : "=v"(r) : "v"(lo), "v"(hi));
  return r;
}

#define GLDS16(g, l) __builtin_amdgcn_global_load_lds( \
    (__attribute__((address_space(1))) void*)(g), \
    (__attribute__((address_space(3))) void*)(l), 16, 0, 0)

// ---------------- prep kernels ----------------

__global__ __launch_bounds__(256) void k_cast_bf16(const float* __restrict__ src,
                                                   unsigned short* __restrict__ dst, int n4) {
  int i = blockIdx.x * 256 + threadIdx.x;
  if (i >= n4) return;
  const float4* s = (const float4*)src;
  float4 v = s[i];
  us4 o = { f2bf(v.x), f2bf(v.y), f2bf(v.z), f2bf(v.w) };
  *(us4*)(dst + (size_t)i * 4) = o;
}

// dst[n*K+k] = bf16(src[k*N+n]); K,N multiples of 64
__global__ __launch_bounds__(256) void k_transpose_bf16(const float* __restrict__ src,
    unsigned short* __restrict__ dst, int K, int N) {
  __shared__ float tile[64][65];
  int k0 = blockIdx.x * 64, n0 = blockIdx.y * 64;
  int t = threadIdx.x;
#pragma unroll
  for (int i = 0; i < 16; ++i) {
    int idx = t + i * 256;
    int r = idx >> 6, c = idx & 63;
    tile[r][c] = src[(size_t)(k0 + r) * N + n0 + c];
  }
  __syncthreads();
#pragma unroll
  for (int i = 0; i < 16; ++i) {
    int idx = t + i * 256;
    int r = idx >> 6, c = idx & 63;
    dst[(size_t)(n0 + r) * K + k0 + c] = f2bf(tile[c][r]);
  }
}

// in-place RoPE on Q (cols 0..2047) and K (cols 2048..2559) of QKV [S][3072]
// Q additionally scaled by log2(e)/sqrt(HD). Uses cos[d+64]==cos[d].
// 4 rotation pairs per thread, vectorized.
__global__ __launch_bounds__(256) void k_rope(unsigned short* __restrict__ QKV,
    const float* __restrict__ cp, const float* __restrict__ sp) {
  int gid = blockIdx.x * 256 + threadIdx.x;   // S*20*16 total
  int d4 = (gid & 15) * 4;
  int hh = (gid >> 4) % 20;
  int s = gid / 320;
  int col = hh < NH ? hh * HD : DMODEL + (hh - NH) * HD;
  float qs = hh < NH ? 0.12751589341664477f : 1.0f;  // log2e/sqrt(128) for Q heads
  size_t base = (size_t)s * LDQKV + col + d4;
  us4 x1 = *(us4*)(QKV + base);
  us4 x2 = *(us4*)(QKV + base + 64);
  float4 c = *(const float4*)(cp + s * HD + d4);
  float4 sn = *(const float4*)(sp + s * HD + d4);
  us4 o1, o2;
  o1[0] = f2bf((bf2f(x1[0]) * c.x - bf2f(x2[0]) * sn.x) * qs);
  o1[1] = f2bf((bf2f(x1[1]) * c.y - bf2f(x2[1]) * sn.y) * qs);
  o1[2] = f2bf((bf2f(x1[2]) * c.z - bf2f(x2[2]) * sn.z) * qs);
  o1[3] = f2bf((bf2f(x1[3]) * c.w - bf2f(x2[3]) * sn.w) * qs);
  o2[0] = f2bf((bf2f(x2[0]) * c.x + bf2f(x1[0]) * sn.x) * qs);
  o2[1] = f2bf((bf2f(x2[1]) * c.y + bf2f(x1[1]) * sn.y) * qs);
  o2[2] = f2bf((bf2f(x2[2]) * c.z + bf2f(x1[2]) * sn.z) * qs);
  o2[3] = f2bf((bf2f(x2[3]) * c.w + bf2f(x1[3]) * sn.w) * qs);
  *(us4*)(QKV + base) = o1;
  *(us4*)(QKV + base + 64) = o2;
}

// Vt[(kvh*128+d)*S + blk*64 + c] = QKV[blk*64 + pi(c)][2560 + kvh*128 + d]
// pi(c) = (c&3)*16 + (c>>2)  — k-permutation matching the P storage layout.
__global__ __launch_bounds__(256) void k_transpose_v(const unsigned short* __restrict__ QKV,
    unsigned short* __restrict__ Vt) {
  __shared__ unsigned short tile[64][72];
  int s0 = blockIdx.x * 64, c0 = blockIdx.y * 64;
  int t = threadIdx.x;
#pragma unroll
  for (int i = 0; i < 16; ++i) {
    int idx = t + i * 256;
    int r = idx >> 6, c = idx & 63;
    tile[r][c] = QKV[(size_t)(s0 + r) * LDQKV + DMODEL + NKVH * HD + c0 + c];
  }
  __syncthreads();
#pragma unroll
  for (int i = 0; i < 16; ++i) {
    int idx = t + i * 256;
    int r = idx >> 6, c = idx & 63;
    int pc = (c & 3) * 16 + (c >> 2);
    Vt[(size_t)(c0 + r) * S_LEN + s0 + c] = tile[pc][r];
  }
}

// ---------------- GEMM: C[M][N] = A[M][K] * Bt[N][K]^T ----------------

template<int OUTF32>
__global__ __launch_bounds__(256) void k_gemm_bt(
    const unsigned short* __restrict__ A, const unsigned short* __restrict__ Bt,
    void* __restrict__ Cp, int M, int N, int K) {
  __shared__ __attribute__((aligned(16))) unsigned short As[128 * 32];
  __shared__ __attribute__((aligned(16))) unsigned short Bs[128 * 32];
  const int t = threadIdx.x;
  const int wave = t >> 6, lane = t & 63;
  const int lr = lane & 15, lg = lane >> 4;
  const int bm = blockIdx.x * 128, bn = blockIdx.y * 128;
  const int wr = (wave >> 1) * 64, wc = (wave & 1) * 64;
  f32x4 acc[4][4];
#pragma unroll
  for (int i = 0; i < 4; ++i)
#pragma unroll
    for (int j = 0; j < 4; ++j) acc[i][j] = (f32x4){0.f, 0.f, 0.f, 0.f};

  for (int k0 = 0; k0 < K; k0 += 32) {
    __syncthreads();
#pragma unroll
    for (int i = 0; i < 2; ++i) {
      const int cb = (wave * 2 + i) * 64;
      const int c = cb + lane;
      const int row = c >> 2, kc = c & 3;
      const int ksw = (kc ^ (row & 3)) * 8;
      GLDS16(A + (size_t)(bm + row) * K + k0 + ksw, (char*)As + cb * 16);
      GLDS16(Bt + (size_t)(bn + row) * K + k0 + ksw, (char*)Bs + cb * 16);
    }
    asm volatile("s_waitcnt vmcnt(0)" ::: "memory");
    __syncthreads();
    bf16x8 af[4], bfr[4];
#pragma unroll
    for (int mi = 0; mi < 4; ++mi) {
      const int row = wr + mi * 16 + lr;
      af[mi] = *(const bf16x8*)(As + row * 32 + ((lg ^ (lr & 3)) * 8));
    }
#pragma unroll
    for (int ni = 0; ni < 4; ++ni) {
      const int row = wc + ni * 16 + lr;
      bfr[ni] = *(const bf16x8*)(Bs + row * 32 + ((lg ^ (lr & 3)) * 8));
    }
#pragma unroll
    for (int mi = 0; mi < 4; ++mi)
#pragma unroll
      for (int ni = 0; ni < 4; ++ni)
        acc[mi][ni] = __builtin_amdgcn_mfma_f32_16x16x32_bf16(af[mi], bfr[ni], acc[mi][ni], 0, 0, 0);
  }
#pragma unroll
  for (int mi = 0; mi < 4; ++mi)
#pragma unroll
    for (int ni = 0; ni < 4; ++ni)
#pragma unroll
      for (int r = 0; r < 4; ++r) {
        const int m = bm + wr + mi * 16 + lg * 4 + r;
        const int n = bn + wc + ni * 16 + lr;
        if (OUTF32) ((float*)Cp)[(size_t)m * N + n] = acc[mi][ni][r];
        else ((unsigned short*)Cp)[(size_t)m * N + n] = f2bf(acc[mi][ni][r]);
      }
}

// ---------------- fused causal gated attention (v4: dual Q-tile) ----------------
// grid (32, NH); block bx streams KV tiles 0..(63-bx) once, serving q-tile
// A = 63-bx for all kt and q-tile B = bx for kt <= bx. 65 tile-computes/block.

#define STAGE_KV(kt_, buf_) do { \
  const int kv0_ = (kt_) * 64; \
  _Pragma("unroll") \
  for (int i_ = 0; i_ < 4; ++i_) { \
    const int cb_ = (wave * 4 + i_) * 64; \
    const int c_ = cb_ + lane; \
    { const int row_ = c_ >> 4, kc_ = c_ & 15; \
      GLDS16(Kp + (size_t)(kv0_ + row_) * LDQKV + ((kc_ ^ (row_ & 7)) * 8), \
             (char*)Ks[buf_] + cb_ * 16); } \
    { const int d_ = c_ >> 3, kc_ = c_ & 7; \
      GLDS16(Vp + (size_t)d_ * S_LEN + kv0_ + ((kc_ ^ (d_ & 7)) * 8), \
             (char*)Vs[buf_] + cb_ * 16); } \
  } \
} while (0)

__device__ __forceinline__ void qkt_pair(const unsigned short* Kb,
    const bf16x8* qfA, const bf16x8* qfB, f32x4* scA, f32x4* scB, int lr, int lg) {
  __builtin_amdgcn_s_setprio(1);
#pragma unroll
  for (int cf = 0; cf < 4; ++cf) {
    scA[cf] = (f32x4){0.f, 0.f, 0.f, 0.f};
    scB[cf] = (f32x4){0.f, 0.f, 0.f, 0.f};
    const int row = cf * 16 + lr;
#pragma unroll
    for (int ks = 0; ks < 4; ++ks) {
      bf16x8 kb = *(const bf16x8*)(Kb + row * 128 + (((ks * 4 + lg) ^ (lr & 7)) * 8));
      scA[cf] = __builtin_amdgcn_mfma_f32_16x16x32_bf16(qfA[ks], kb, scA[cf], 0, 0, 0);
      scB[cf] = __builtin_amdgcn_mfma_f32_16x16x32_bf16(qfB[ks], kb, scB[cf], 0, 0, 0);
    }
  }
  __builtin_amdgcn_s_setprio(0);
}

__device__ __forceinline__ void qkt_one(const unsigned short* Kb,
    const bf16x8* qf, f32x4* sc, int lr, int lg) {
  __builtin_amdgcn_s_setprio(1);
#pragma unroll
  for (int cf = 0; cf < 4; ++cf) {
    sc[cf] = (f32x4){0.f, 0.f, 0.f, 0.f};
    const int row = cf * 16 + lr;
#pragma unroll
    for (int ks = 0; ks < 4; ++ks) {
      bf16x8 kb = *(const bf16x8*)(Kb + row * 128 + (((ks * 4 + lg) ^ (lr & 7)) * 8));
      sc[cf] = __builtin_amdgcn_mfma_f32_16x16x32_bf16(qf[ks], kb, sc[cf], 0, 0, 0);
    }
  }
  __builtin_amdgcn_s_setprio(0);
}

template<bool DIAG>
__device__ __forceinline__ void softmax_pv(
    f32x4* sc, const unsigned short* Vb, unsigned short (*PsW)[72],
    const float* g4, int kv0, int qbase,
    f32x4* acc, f32x4& acc_s, float* mrow, int lr, int lg,
    const bf16x8 vb_ones) {
  if (DIAG) {
#pragma unroll
    for (int cf = 0; cf < 4; ++cf) {
      const int kpos = kv0 + cf * 16 + lr;
#pragma unroll
      for (int r = 0; r < 4; ++r)
        sc[cf][r] = (kpos <= qbase + r) ? sc[cf][r] : -3e38f;
    }
  }
  float lmax[4];
#pragma unroll
  for (int r = 0; r < 4; ++r)
    lmax[r] = fmaxf(fmaxf(sc[0][r], sc[1][r]), fmaxf(sc[2][r], sc[3][r]));

  bool need = (lmax[0] > mrow[0] + 11.5416f) | (lmax[1] > mrow[1] + 11.5416f) |
              (lmax[2] > mrow[2] + 11.5416f) | (lmax[3] > mrow[3] + 11.5416f);
  if (__any(need)) {
    float tm[4] = {lmax[0], lmax[1], lmax[2], lmax[3]};
#pragma unroll
    for (int off = 8; off; off >>= 1)
#pragma unroll
      for (int r = 0; r < 4; ++r) tm[r] = fmaxf(tm[r], __shfl_xor(tm[r], off));
#pragma unroll
    for (int r = 0; r < 4; ++r) {
      const float mn = fmaxf(mrow[r], tm[r]);
      const float alpha = __builtin_amdgcn_exp2f(mrow[r] - mn);
      mrow[r] = mn;
#pragma unroll
      for (int j = 0; j < 8; ++j) acc[j][r] *= alpha;
      acc_s[r] *= alpha;
    }
  }
#pragma unroll
  for (int r = 0; r < 4; ++r) {
    float p0 = __builtin_amdgcn_exp2f(sc[0][r] - mrow[r]) * g4[0];
    float p1 = __builtin_amdgcn_exp2f(sc[1][r] - mrow[r]) * g4[1];
    float p2 = __builtin_amdgcn_exp2f(sc[2][r] - mrow[r]) * g4[2];
    float p3 = __builtin_amdgcn_exp2f(sc[3][r] - mrow[r]) * g4[3];
    uint2 pk = { cvt_pk_bf16(p0, p1), cvt_pk_bf16(p2, p3) };
    *(uint2*)(&PsW[lg * 4 + r][lr * 4]) = pk;
  }
  asm volatile("s_waitcnt lgkmcnt(0)" ::: "memory");
  __builtin_amdgcn_sched_barrier(0);
  __builtin_amdgcn_s_setprio(1);
#pragma unroll
  for (int ks = 0; ks < 2; ++ks) {
    bf16x8 pa = *(const bf16x8*)(&PsW[lr][ks * 32 + lg * 8]);
#pragma unroll
    for (int j = 0; j < 8; ++j) {
      const int d = j * 16 + lr;
      bf16x8 vb = *(const bf16x8*)(Vb + d * 64 + (((ks * 4 + lg) ^ (lr & 7)) * 8));
      acc[j] = __builtin_amdgcn_mfma_f32_16x16x32_bf16(pa, vb, acc[j], 0, 0, 0);
    }
    acc_s = __builtin_amdgcn_mfma_f32_16x16x32_bf16(pa, vb_ones, acc_s, 0, 0, 0);
  }
  __builtin_amdgcn_s_setprio(0);
}

__global__ __launch_bounds__(256) void k_attn(
    const unsigned short* __restrict__ QKV, const unsigned short* __restrict__ Vt,
    const float* __restrict__ gate, unsigned short* __restrict__ Oattn) {
  __shared__ __attribute__((aligned(16))) unsigned short Ks[2][64 * 128];
  __shared__ __attribute__((aligned(16))) unsigned short Vs[2][128 * 64];
  __shared__ __attribute__((aligned(16))) unsigned short Ps[4][16][72];
  const int h = blockIdx.y, kvh = h >> 2;
  const int bx = blockIdx.x;           // 0..31
  const int t = threadIdx.x, wave = t >> 6, lane = t & 63;
  const int lr = lane & 15, lg = lane >> 4;
  const unsigned short* Qp = QKV + h * HD;
  const unsigned short* Kp = QKV + DMODEL + kvh * HD;
  const unsigned short* Vp = Vt + (size_t)kvh * HD * S_LEN;
  unsigned short (*PsW)[72] = Ps[wave];
  bf16x8 vb_ones;
  {
    const short one = (short)0x3F80, z = 0;
    const short e = (lr == 0) ? one : z;
    vb_ones = (bf16x8){e, e, e, e, e, e, e, e};
  }

  const int qtA = 63 - bx, qtB = bx;   // qtA >= 32 > qtB always
  const int qbaseA = qtA * 64 + wave * 16 + lg * 4;
  const int qbaseB = qtB * 64 + wave * 16 + lg * 4;

  bf16x8 qfA[4], qfB[4];
  {
    const size_t offA = (size_t)(qtA * 64 + wave * 16 + lr) * LDQKV;
    const size_t offB = (size_t)(qtB * 64 + wave * 16 + lr) * LDQKV;
#pragma unroll
    for (int ks = 0; ks < 4; ++ks) {
      qfA[ks] = *(const bf16x8*)(Qp + offA + ks * 32 + lg * 8);
      qfB[ks] = *(const bf16x8*)(Qp + offB + ks * 32 + lg * 8);
    }
  }
  f32x4 accA[8], accB[8];
#pragma unroll
  for (int j = 0; j < 8; ++j) {
    accA[j] = (f32x4){0.f, 0.f, 0.f, 0.f};
    accB[j] = (f32x4){0.f, 0.f, 0.f, 0.f};
  }
  f32x4 acc_sA = (f32x4){0.f, 0.f, 0.f, 0.f};
  f32x4 acc_sB = (f32x4){0.f, 0.f, 0.f, 0.f};
  float mrowA[4] = {-3e38f, -3e38f, -3e38f, -3e38f};
  float mrowB[4] = {-3e38f, -3e38f, -3e38f, -3e38f};

  STAGE_KV(0, 0);

  f32x4 scA[4], scB[4];
  float g4[4];
  int kt = 0;
  // dual region, B interior: kt < qtB
  for (; kt < qtB; ++kt) {
    STAGE_KV(kt + 1, (kt + 1) & 1);
    asm volatile("s_waitcnt vmcnt(8)" ::: "memory");
    __builtin_amdgcn_s_barrier();
    const unsigned short* Kb = Ks[kt & 1];
    const unsigned short* Vb = Vs[kt & 1];
#pragma unroll
    for (int cf = 0; cf < 4; ++cf) g4[cf] = gate[kt * 64 + cf * 16 + lr];
    qkt_pair(Kb, qfA, qfB, scA, scB, lr, lg);
    softmax_pv<false>(scA, Vb, PsW, g4, kt * 64, qbaseA, accA, acc_sA, mrowA, lr, lg, vb_ones);
    softmax_pv<false>(scB, Vb, PsW, g4, kt * 64, qbaseB, accB, acc_sB, mrowB, lr, lg, vb_ones);
    __builtin_amdgcn_s_barrier();
  }
  // kt == qtB: dual, B diagonal (stage kt+1 always valid: qtB+1 <= qtA)
  {
    STAGE_KV(kt + 1, (kt + 1) & 1);
    asm volatile("s_waitcnt vmcnt(8)" ::: "memory");
    __builtin_amdgcn_s_barrier();
    const unsigned short* Kb = Ks[kt & 1];
    const unsigned short* Vb = Vs[kt & 1];
#pragma unroll
    for (int cf = 0; cf < 4; ++cf) g4[cf] = gate[kt * 64 + cf * 16 + lr];
    qkt_pair(Kb, qfA, qfB, scA, scB, lr, lg);
    softmax_pv<false>(scA, Vb, PsW, g4, kt * 64, qbaseA, accA, acc_sA, mrowA, lr, lg, vb_ones);
    softmax_pv<true>(scB, Vb, PsW, g4, kt * 64, qbaseB, accB, acc_sB, mrowB, lr, lg, vb_ones);
    __builtin_amdgcn_s_barrier();
    ++kt;
  }
  // single-A region: qtB < kt < qtA
  for (; kt < qtA; ++kt) {
    STAGE_KV(kt + 1, (kt + 1) & 1);
    asm volatile("s_waitcnt vmcnt(8)" ::: "memory");
    __builtin_amdgcn_s_barrier();
    const unsigned short* Kb = Ks[kt & 1];
    const unsigned short* Vb = Vs[kt & 1];
#pragma unroll
    for (int cf = 0; cf < 4; ++cf) g4[cf] = gate[kt * 64 + cf * 16 + lr];
    qkt_one(Kb, qfA, scA, lr, lg);
    softmax_pv<false>(scA, Vb, PsW, g4, kt * 64, qbaseA, accA, acc_sA, mrowA, lr, lg, vb_ones);
    __builtin_amdgcn_s_barrier();
  }
  // kt == qtA: single, A diagonal, nothing left to stage
  {
    asm volatile("s_waitcnt vmcnt(0)" ::: "memory");
    __builtin_amdgcn_s_barrier();
    const unsigned short* Kb = Ks[kt & 1];
    const unsigned short* Vb = Vs[kt & 1];
#pragma unroll
    for (int cf = 0; cf < 4; ++cf) g4[cf] = gate[kt * 64 + cf * 16 + lr];
    qkt_one(Kb, qfA, scA, lr, lg);
    softmax_pv<true>(scA, Vb, PsW, g4, kt * 64, qbaseA, accA, acc_sA, mrowA, lr, lg, vb_ones);
  }

  // epilogue: normalize and store both q-tiles
  float invA[4], invB[4];
#pragma unroll
  for (int r = 0; r < 4; ++r) {
    invA[r] = 1.0f / __shfl(acc_sA[r], lane & 48);
    invB[r] = 1.0f / __shfl(acc_sB[r], lane & 48);
  }
#pragma unroll
  for (int j = 0; j < 8; ++j)
#pragma unroll
    for (int r = 0; r < 4; ++r) {
      Oattn[(size_t)(qbaseA + r) * DMODEL + h * HD + j * 16 + lr] = f2bf(accA[j][r] * invA[r]);
      Oattn[(size_t)(qbaseB + r) * DMODEL + h * HD + j * 16 + lr] = f2bf(accB[j][r] * invB[r]);
    }
}

// ---------------- launch ----------------

extern "C" void kernel_launch(void* const* d_in, const int* in_sizes, int n_in,
                              void* d_out, int out_size, void* d_ws, size_t ws_size,
                              hipStream_t stream) {
  (void)in_sizes; (void)n_in; (void)out_size; (void)ws_size;
  const float* hid  = (const float*)d_in[0];
  // d_in[1] = attention_mask (pure causal; recomputed inline, never read)
  const float* cosp = (const float*)d_in[2];
  const float* sinp = (const float*)d_in[3];
  const float* gate = (const float*)d_in[4];
  const float* Wq   = (const float*)d_in[5];
  const float* Wk   = (const float*)d_in[6];
  const float* Wv   = (const float*)d_in[7];
  const float* Wo   = (const float*)d_in[8];
  float* out = (float*)d_out;
  char* ws = (char*)d_ws;
  unsigned short* Xb   = (unsigned short*)(ws);                       // 16 MB  [4096][2048] bf16
  unsigned short* Wt   = (unsigned short*)(ws + (size_t)16777216);    // 12 MB  [3072][2048] bf16 (Wq|Wk|Wv)^T
  unsigned short* Wot  = (unsigned short*)(ws + (size_t)29360128);    //  8 MB  [2048][2048] bf16 Wo^T
  unsigned short* QKV  = (unsigned short*)(ws + (size_t)37748736);    // 24 MB  [4096][3072] bf16
  unsigned short* Oatt = (unsigned short*)(ws + (size_t)62914560);    // 16 MB  [4096][2048] bf16
  unsigned short* Vt   = (unsigned short*)(ws + (size_t)79691776);    //  4 MB  [4][128][4096] bf16

  k_cast_bf16<<<8192, 256, 0, stream>>>(hid, Xb, 2097152);
  k_transpose_bf16<<<dim3(32, 32), 256, 0, stream>>>(Wq, Wt, 2048, 2048);
  k_transpose_bf16<<<dim3(32, 8), 256, 0, stream>>>(Wk, Wt + (size_t)2048 * 2048, 2048, 512);
  k_transpose_bf16<<<dim3(32, 8), 256, 0, stream>>>(Wv, Wt + (size_t)2560 * 2048, 2048, 512);
  k_transpose_bf16<<<dim3(32, 32), 256, 0, stream>>>(Wo, Wot, 2048, 2048);
  k_gemm_bt<0><<<dim3(32, 24), 256, 0, stream>>>(Xb, Wt, QKV, 4096, 3072, 2048);
  k_rope<<<5120, 256, 0, stream>>>(QKV, cosp, sinp);
  k_transpose_v<<<dim3(64, 8), 256, 0, stream>>>(QKV, Vt);
  k_attn<<<dim3(32, 16), 256, 0, stream>>>(QKV, Vt, gate, Oatt);
  k_gemm_bt<1><<<dim3(32, 16), 256, 0, stream>>>(Oatt, Wot, out, 4096, 2048, 2048);
}

// Round 5
// 284.339 us; speedup vs baseline: 1.2996x; 1.2996x over previous
//
#include <hip/hip_runtime.h>
#include <math.h>

#define S_LEN 4096
#define DMODEL 2048
#define NH 16
#define NKVH 4
#define HD 128
#define LDQKV 3072   // NH*HD + 2*NKVH*HD

typedef __attribute__((ext_vector_type(4))) float f32x4;
typedef __attribute__((ext_vector_type(8))) short bf16x8;
typedef __attribute__((ext_vector_type(4))) unsigned short us4;

static __device__ __forceinline__ unsigned short f2bf(float f) {
  unsigned int u = __builtin_bit_cast(unsigned int, f);
  u += 0x7fffu + ((u >> 16) & 1u);
  return (unsigned short)(u >> 16);
}
static __device__ __forceinline__ float bf2f(unsigned short h) {
  unsigned int u = ((unsigned int)h) << 16;
  return __builtin_bit_cast(float, u);
}
static __device__ __forceinline__ unsigned int cvt_pk_bf16(float lo, float hi) {
  unsigned int r;
  asm("v_cvt_pk_bf16_f32 %0, %1, %2" : "=v"(r) : "v"(lo), "v"(hi));
  return r;
}

#define GLDS16(g, l) __builtin_amdgcn_global_load_lds( \
    (__attribute__((address_space(1))) void*)(g), \
    (__attribute__((address_space(3))) void*)(l), 16, 0, 0)

// ---------------- prep kernels ----------------

__global__ __launch_bounds__(256) void k_cast_bf16(const float* __restrict__ src,
                                                   unsigned short* __restrict__ dst, int n4) {
  int i = blockIdx.x * 256 + threadIdx.x;
  if (i >= n4) return;
  const float4* s = (const float4*)src;
  float4 v = s[i];
  us4 o = { f2bf(v.x), f2bf(v.y), f2bf(v.z), f2bf(v.w) };
  *(us4*)(dst + (size_t)i * 4) = o;
}

// dst[n*K+k] = bf16(src[k*N+n]); K,N multiples of 64
__global__ __launch_bounds__(256) void k_transpose_bf16(const float* __restrict__ src,
    unsigned short* __restrict__ dst, int K, int N) {
  __shared__ float tile[64][65];
  int k0 = blockIdx.x * 64, n0 = blockIdx.y * 64;
  int t = threadIdx.x;
#pragma unroll
  for (int i = 0; i < 16; ++i) {
    int idx = t + i * 256;
    int r = idx >> 6, c = idx & 63;
    tile[r][c] = src[(size_t)(k0 + r) * N + n0 + c];
  }
  __syncthreads();
#pragma unroll
  for (int i = 0; i < 16; ++i) {
    int idx = t + i * 256;
    int r = idx >> 6, c = idx & 63;
    dst[(size_t)(n0 + r) * K + k0 + c] = f2bf(tile[c][r]);
  }
}

// in-place RoPE on Q (cols 0..2047) and K (cols 2048..2559) of QKV [S][3072]
// Q additionally scaled by log2(e)/sqrt(HD). Uses cos[d+64]==cos[d].
__global__ __launch_bounds__(256) void k_rope(unsigned short* __restrict__ QKV,
    const float* __restrict__ cp, const float* __restrict__ sp) {
  int gid = blockIdx.x * 256 + threadIdx.x;   // S*20*16 total
  int d4 = (gid & 15) * 4;
  int hh = (gid >> 4) % 20;
  int s = gid / 320;
  int col = hh < NH ? hh * HD : DMODEL + (hh - NH) * HD;
  float qs = hh < NH ? 0.12751589341664477f : 1.0f;  // log2e/sqrt(128) for Q heads
  size_t base = (size_t)s * LDQKV + col + d4;
  us4 x1 = *(us4*)(QKV + base);
  us4 x2 = *(us4*)(QKV + base + 64);
  float4 c = *(const float4*)(cp + s * HD + d4);
  float4 sn = *(const float4*)(sp + s * HD + d4);
  us4 o1, o2;
  o1[0] = f2bf((bf2f(x1[0]) * c.x - bf2f(x2[0]) * sn.x) * qs);
  o1[1] = f2bf((bf2f(x1[1]) * c.y - bf2f(x2[1]) * sn.y) * qs);
  o1[2] = f2bf((bf2f(x1[2]) * c.z - bf2f(x2[2]) * sn.z) * qs);
  o1[3] = f2bf((bf2f(x1[3]) * c.w - bf2f(x2[3]) * sn.w) * qs);
  o2[0] = f2bf((bf2f(x2[0]) * c.x + bf2f(x1[0]) * sn.x) * qs);
  o2[1] = f2bf((bf2f(x2[1]) * c.y + bf2f(x1[1]) * sn.y) * qs);
  o2[2] = f2bf((bf2f(x2[2]) * c.z + bf2f(x1[2]) * sn.z) * qs);
  o2[3] = f2bf((bf2f(x2[3]) * c.w + bf2f(x1[3]) * sn.w) * qs);
  *(us4*)(QKV + base) = o1;
  *(us4*)(QKV + base + 64) = o2;
}

// Vt[(kvh*128+d)*S + blk*64 + c] = QKV[blk*64 + pi(c)][2560 + kvh*128 + d]
// pi(c) = (c&3)*16 + (c>>2)  — k-permutation matching the P storage layout.
__global__ __launch_bounds__(256) void k_transpose_v(const unsigned short* __restrict__ QKV,
    unsigned short* __restrict__ Vt) {
  __shared__ unsigned short tile[64][72];
  int s0 = blockIdx.x * 64, c0 = blockIdx.y * 64;
  int t = threadIdx.x;
#pragma unroll
  for (int i = 0; i < 16; ++i) {
    int idx = t + i * 256;
    int r = idx >> 6, c = idx & 63;
    tile[r][c] = QKV[(size_t)(s0 + r) * LDQKV + DMODEL + NKVH * HD + c0 + c];
  }
  __syncthreads();
#pragma unroll
  for (int i = 0; i < 16; ++i) {
    int idx = t + i * 256;
    int r = idx >> 6, c = idx & 63;
    int pc = (c & 3) * 16 + (c >> 2);
    Vt[(size_t)(c0 + r) * S_LEN + s0 + c] = tile[pc][r];
  }
}

// ---------------- GEMM: C[M][N] = A[M][K] * Bt[N][K]^T ----------------

template<int OUTF32>
__global__ __launch_bounds__(256) void k_gemm_bt(
    const unsigned short* __restrict__ A, const unsigned short* __restrict__ Bt,
    void* __restrict__ Cp, int M, int N, int K) {
  __shared__ __attribute__((aligned(16))) unsigned short As[128 * 32];
  __shared__ __attribute__((aligned(16))) unsigned short Bs[128 * 32];
  const int t = threadIdx.x;
  const int wave = t >> 6, lane = t & 63;
  const int lr = lane & 15, lg = lane >> 4;
  const int bm = blockIdx.x * 128, bn = blockIdx.y * 128;
  const int wr = (wave >> 1) * 64, wc = (wave & 1) * 64;
  f32x4 acc[4][4];
#pragma unroll
  for (int i = 0; i < 4; ++i)
#pragma unroll
    for (int j = 0; j < 4; ++j) acc[i][j] = (f32x4){0.f, 0.f, 0.f, 0.f};

  for (int k0 = 0; k0 < K; k0 += 32) {
    __syncthreads();
#pragma unroll
    for (int i = 0; i < 2; ++i) {
      const int cb = (wave * 2 + i) * 64;
      const int c = cb + lane;
      const int row = c >> 2, kc = c & 3;
      const int ksw = (kc ^ (row & 3)) * 8;
      GLDS16(A + (size_t)(bm + row) * K + k0 + ksw, (char*)As + cb * 16);
      GLDS16(Bt + (size_t)(bn + row) * K + k0 + ksw, (char*)Bs + cb * 16);
    }
    asm volatile("s_waitcnt vmcnt(0)" ::: "memory");
    __syncthreads();
    bf16x8 af[4], bfr[4];
#pragma unroll
    for (int mi = 0; mi < 4; ++mi) {
      const int row = wr + mi * 16 + lr;
      af[mi] = *(const bf16x8*)(As + row * 32 + ((lg ^ (lr & 3)) * 8));
    }
#pragma unroll
    for (int ni = 0; ni < 4; ++ni) {
      const int row = wc + ni * 16 + lr;
      bfr[ni] = *(const bf16x8*)(Bs + row * 32 + ((lg ^ (lr & 3)) * 8));
    }
#pragma unroll
    for (int mi = 0; mi < 4; ++mi)
#pragma unroll
      for (int ni = 0; ni < 4; ++ni)
        acc[mi][ni] = __builtin_amdgcn_mfma_f32_16x16x32_bf16(af[mi], bfr[ni], acc[mi][ni], 0, 0, 0);
  }
#pragma unroll
  for (int mi = 0; mi < 4; ++mi)
#pragma unroll
    for (int ni = 0; ni < 4; ++ni)
#pragma unroll
      for (int r = 0; r < 4; ++r) {
        const int m = bm + wr + mi * 16 + lg * 4 + r;
        const int n = bn + wc + ni * 16 + lr;
        if (OUTF32) ((float*)Cp)[(size_t)m * N + n] = acc[mi][ni][r];
        else ((unsigned short*)Cp)[(size_t)m * N + n] = f2bf(acc[mi][ni][r]);
      }
}

// ---------------- fused causal gated attention (v5: 8-wave, 128 q-rows/block) ----------------
// grid (16, NH), 512 threads. Block bx serves q-super-tiles A=31-bx then B=bx
// (128 rows each); one staged K/V tile feeds all 8 waves. 68 iterations/block.

#define STAGE_KV(kt_, buf_) do { \
  const int kv0_ = (kt_) * 64; \
  _Pragma("unroll") \
  for (int i_ = 0; i_ < 2; ++i_) { \
    const int cb_ = (wave * 2 + i_) * 64; \
    const int c_ = cb_ + lane; \
    { const int row_ = c_ >> 4, kc_ = c_ & 15; \
      GLDS16(Kp + (size_t)(kv0_ + row_) * LDQKV + ((kc_ ^ (row_ & 7)) * 8), \
             (char*)Ks[buf_] + cb_ * 16); } \
    { const int d_ = c_ >> 3, kc_ = c_ & 7; \
      GLDS16(Vp + (size_t)d_ * S_LEN + kv0_ + ((kc_ ^ (d_ & 7)) * 8), \
             (char*)Vs[buf_] + cb_ * 16); } \
  } \
} while (0)

__device__ __forceinline__ void qkt_one(const unsigned short* Kb,
    const bf16x8* qf, f32x4* sc, int lr, int lg) {
  __builtin_amdgcn_s_setprio(1);
#pragma unroll
  for (int cf = 0; cf < 4; ++cf) {
    sc[cf] = (f32x4){0.f, 0.f, 0.f, 0.f};
    const int row = cf * 16 + lr;
#pragma unroll
    for (int ks = 0; ks < 4; ++ks) {
      bf16x8 kb = *(const bf16x8*)(Kb + row * 128 + (((ks * 4 + lg) ^ (lr & 7)) * 8));
      sc[cf] = __builtin_amdgcn_mfma_f32_16x16x32_bf16(qf[ks], kb, sc[cf], 0, 0, 0);
    }
  }
  __builtin_amdgcn_s_setprio(0);
}

template<bool DIAG>
__device__ __forceinline__ void softmax_pv(
    f32x4* sc, const unsigned short* Vb, unsigned short (*PsW)[72],
    const float* g4, int kv0, int qbase,
    f32x4* acc, f32x4& acc_s, float* mrow, int lr, int lg,
    const bf16x8 vb_ones) {
  if (DIAG) {
#pragma unroll
    for (int cf = 0; cf < 4; ++cf) {
      const int kpos = kv0 + cf * 16 + lr;
#pragma unroll
      for (int r = 0; r < 4; ++r)
        sc[cf][r] = (kpos <= qbase + r) ? sc[cf][r] : -3e38f;
    }
  }
  float lmax[4];
#pragma unroll
  for (int r = 0; r < 4; ++r)
    lmax[r] = fmaxf(fmaxf(sc[0][r], sc[1][r]), fmaxf(sc[2][r], sc[3][r]));

  bool need = (lmax[0] > mrow[0] + 11.5416f) | (lmax[1] > mrow[1] + 11.5416f) |
              (lmax[2] > mrow[2] + 11.5416f) | (lmax[3] > mrow[3] + 11.5416f);
  if (__any(need)) {
    float tm[4] = {lmax[0], lmax[1], lmax[2], lmax[3]};
#pragma unroll
    for (int off = 8; off; off >>= 1)
#pragma unroll
      for (int r = 0; r < 4; ++r) tm[r] = fmaxf(tm[r], __shfl_xor(tm[r], off));
#pragma unroll
    for (int r = 0; r < 4; ++r) {
      const float mn = fmaxf(mrow[r], tm[r]);
      const float alpha = __builtin_amdgcn_exp2f(mrow[r] - mn);
      mrow[r] = mn;
#pragma unroll
      for (int j = 0; j < 8; ++j) acc[j][r] *= alpha;
      acc_s[r] *= alpha;
    }
  }
#pragma unroll
  for (int r = 0; r < 4; ++r) {
    float p0 = __builtin_amdgcn_exp2f(sc[0][r] - mrow[r]) * g4[0];
    float p1 = __builtin_amdgcn_exp2f(sc[1][r] - mrow[r]) * g4[1];
    float p2 = __builtin_amdgcn_exp2f(sc[2][r] - mrow[r]) * g4[2];
    float p3 = __builtin_amdgcn_exp2f(sc[3][r] - mrow[r]) * g4[3];
    uint2 pk = { cvt_pk_bf16(p0, p1), cvt_pk_bf16(p2, p3) };
    *(uint2*)(&PsW[lg * 4 + r][lr * 4]) = pk;
  }
  asm volatile("s_waitcnt lgkmcnt(0)" ::: "memory");
  __builtin_amdgcn_sched_barrier(0);
  __builtin_amdgcn_s_setprio(1);
#pragma unroll
  for (int ks = 0; ks < 2; ++ks) {
    bf16x8 pa = *(const bf16x8*)(&PsW[lr][ks * 32 + lg * 8]);
#pragma unroll
    for (int j = 0; j < 8; ++j) {
      const int d = j * 16 + lr;
      bf16x8 vb = *(const bf16x8*)(Vb + d * 64 + (((ks * 4 + lg) ^ (lr & 7)) * 8));
      acc[j] = __builtin_amdgcn_mfma_f32_16x16x32_bf16(pa, vb, acc[j], 0, 0, 0);
    }
    acc_s = __builtin_amdgcn_mfma_f32_16x16x32_bf16(pa, vb_ones, acc_s, 0, 0, 0);
  }
  __builtin_amdgcn_s_setprio(0);
}

__global__ __launch_bounds__(512) void k_attn(
    const unsigned short* __restrict__ QKV, const unsigned short* __restrict__ Vt,
    const float* __restrict__ gate, unsigned short* __restrict__ Oattn) {
  __shared__ __attribute__((aligned(16))) unsigned short Ks[2][64 * 128];
  __shared__ __attribute__((aligned(16))) unsigned short Vs[2][128 * 64];
  __shared__ __attribute__((aligned(16))) unsigned short Ps[8][16][72];
  const int h = blockIdx.y, kvh = h >> 2;
  const int bx = blockIdx.x;           // 0..15
  const int t = threadIdx.x, wave = t >> 6, lane = t & 63;
  const int lr = lane & 15, lg = lane >> 4;
  const unsigned short* Qp = QKV + h * HD;
  const unsigned short* Kp = QKV + DMODEL + kvh * HD;
  const unsigned short* Vp = Vt + (size_t)kvh * HD * S_LEN;
  unsigned short (*PsW)[72] = Ps[wave];
  bf16x8 vb_ones;
  {
    const short one = (short)0x3F80, z = 0;
    const short e = (lr == 0) ? one : z;
    vb_ones = (bf16x8){e, e, e, e, e, e, e, e};
  }

  for (int half = 0; half < 2; ++half) {
    const int st = half ? bx : (31 - bx);   // super-tile (128 rows), heavy first
    const int q0 = st * 128;
    const int nt = st * 2 + 2;              // KV tiles 0..nt-1
    const int qbase = q0 + wave * 16 + lg * 4;
    const int wrow_last = q0 + wave * 16 + 15;

    bf16x8 qf[4];
    {
      const size_t qoff = (size_t)(q0 + wave * 16 + lr) * LDQKV;
#pragma unroll
      for (int ks = 0; ks < 4; ++ks)
        qf[ks] = *(const bf16x8*)(Qp + qoff + ks * 32 + lg * 8);
    }
    f32x4 acc[8];
#pragma unroll
    for (int j = 0; j < 8; ++j) acc[j] = (f32x4){0.f, 0.f, 0.f, 0.f};
    f32x4 acc_s = (f32x4){0.f, 0.f, 0.f, 0.f};
    float mrow[4] = {-3e38f, -3e38f, -3e38f, -3e38f};
    f32x4 sc[4];
    float g4[4];

    __builtin_amdgcn_s_barrier();        // protect buf0 from previous half's reads
    STAGE_KV(0, 0);

    int kt = 0;
    // interior tiles (never masked: kv0 < q0)
    for (; kt < nt - 2; ++kt) {
      STAGE_KV(kt + 1, (kt + 1) & 1);
      asm volatile("s_waitcnt vmcnt(4)" ::: "memory");
      __builtin_amdgcn_s_barrier();
#pragma unroll
      for (int cf = 0; cf < 4; ++cf) g4[cf] = gate[kt * 64 + cf * 16 + lr];
      qkt_one(Ks[kt & 1], qf, sc, lr, lg);
      softmax_pv<false>(sc, Vs[kt & 1], PsW, g4, kt * 64, qbase, acc, acc_s, mrow, lr, lg, vb_ones);
      __builtin_amdgcn_s_barrier();
    }
    // kt == nt-2 (kv0 == q0): diagonal for waves 0-3, full for 4-7; stage last tile
    {
      STAGE_KV(kt + 1, (kt + 1) & 1);
      asm volatile("s_waitcnt vmcnt(4)" ::: "memory");
      __builtin_amdgcn_s_barrier();
#pragma unroll
      for (int cf = 0; cf < 4; ++cf) g4[cf] = gate[kt * 64 + cf * 16 + lr];
      qkt_one(Ks[kt & 1], qf, sc, lr, lg);
      softmax_pv<true>(sc, Vs[kt & 1], PsW, g4, kt * 64, qbase, acc, acc_s, mrow, lr, lg, vb_ones);
      __builtin_amdgcn_s_barrier();
      ++kt;
    }
    // kt == nt-1 (kv0 == q0+64): only waves with rows >= kv0 participate
    {
      const int kv0 = kt * 64;
      asm volatile("s_waitcnt vmcnt(0)" ::: "memory");
      __builtin_amdgcn_s_barrier();
      if (kv0 <= wrow_last) {
#pragma unroll
        for (int cf = 0; cf < 4; ++cf) g4[cf] = gate[kv0 + cf * 16 + lr];
        qkt_one(Ks[kt & 1], qf, sc, lr, lg);
        softmax_pv<true>(sc, Vs[kt & 1], PsW, g4, kv0, qbase, acc, acc_s, mrow, lr, lg, vb_ones);
      }
    }

    float inv[4];
#pragma unroll
    for (int r = 0; r < 4; ++r)
      inv[r] = 1.0f / __shfl(acc_s[r], lane & 48);
#pragma unroll
    for (int j = 0; j < 8; ++j)
#pragma unroll
      for (int r = 0; r < 4; ++r)
        Oattn[(size_t)(qbase + r) * DMODEL + h * HD + j * 16 + lr] = f2bf(acc[j][r] * inv[r]);
  }
}

// ---------------- launch ----------------

extern "C" void kernel_launch(void* const* d_in, const int* in_sizes, int n_in,
                              void* d_out, int out_size, void* d_ws, size_t ws_size,
                              hipStream_t stream) {
  (void)in_sizes; (void)n_in; (void)out_size; (void)ws_size;
  const float* hid  = (const float*)d_in[0];
  // d_in[1] = attention_mask (pure causal; recomputed inline, never read)
  const float* cosp = (const float*)d_in[2];
  const float* sinp = (const float*)d_in[3];
  const float* gate = (const float*)d_in[4];
  const float* Wq   = (const float*)d_in[5];
  const float* Wk   = (const float*)d_in[6];
  const float* Wv   = (const float*)d_in[7];
  const float* Wo   = (const float*)d_in[8];
  float* out = (float*)d_out;
  char* ws = (char*)d_ws;
  unsigned short* Xb   = (unsigned short*)(ws);                       // 16 MB  [4096][2048] bf16
  unsigned short* Wt   = (unsigned short*)(ws + (size_t)16777216);    // 12 MB  [3072][2048] bf16 (Wq|Wk|Wv)^T
  unsigned short* Wot  = (unsigned short*)(ws + (size_t)29360128);    //  8 MB  [2048][2048] bf16 Wo^T
  unsigned short* QKV  = (unsigned short*)(ws + (size_t)37748736);    // 24 MB  [4096][3072] bf16
  unsigned short* Oatt = (unsigned short*)(ws + (size_t)62914560);    // 16 MB  [4096][2048] bf16
  unsigned short* Vt   = (unsigned short*)(ws + (size_t)79691776);    //  4 MB  [4][128][4096] bf16

  k_cast_bf16<<<8192, 256, 0, stream>>>(hid, Xb, 2097152);
  k_transpose_bf16<<<dim3(32, 32), 256, 0, stream>>>(Wq, Wt, 2048, 2048);
  k_transpose_bf16<<<dim3(32, 8), 256, 0, stream>>>(Wk, Wt + (size_t)2048 * 2048, 2048, 512);
  k_transpose_bf16<<<dim3(32, 8), 256, 0, stream>>>(Wv, Wt + (size_t)2560 * 2048, 2048, 512);
  k_transpose_bf16<<<dim3(32, 32), 256, 0, stream>>>(Wo, Wot, 2048, 2048);
  k_gemm_bt<0><<<dim3(32, 24), 256, 0, stream>>>(Xb, Wt, QKV, 4096, 3072, 2048);
  k_rope<<<5120, 256, 0, stream>>>(QKV, cosp, sinp);
  k_transpose_v<<<dim3(64, 8), 256, 0, stream>>>(QKV, Vt);
  k_attn<<<dim3(16, 16), 512, 0, stream>>>(QKV, Vt, gate, Oatt);
  k_gemm_bt<1><<<dim3(32, 16), 256, 0, stream>>>(Oatt, Wot, out, 4096, 2048, 2048);
}

// Round 6
// 269.015 us; speedup vs baseline: 1.3736x; 1.0570x over previous
//
#include <hip/hip_runtime.h>
#include <math.h>

#define S_LEN 4096
#define DMODEL 2048
#define NH 16
#define NKVH 4
#define HD 128
#define LDQKV 3072   // NH*HD + 2*NKVH*HD

typedef __attribute__((ext_vector_type(4))) float f32x4;
typedef __attribute__((ext_vector_type(8))) short bf16x8;
typedef __attribute__((ext_vector_type(4))) unsigned short us4;

static __device__ __forceinline__ unsigned short f2bf(float f) {
  unsigned int u = __builtin_bit_cast(unsigned int, f);
  u += 0x7fffu + ((u >> 16) & 1u);
  return (unsigned short)(u >> 16);
}
static __device__ __forceinline__ float bf2f(unsigned short h) {
  unsigned int u = ((unsigned int)h) << 16;
  return __builtin_bit_cast(float, u);
}
static __device__ __forceinline__ unsigned int cvt_pk_bf16(float lo, float hi) {
  unsigned int r;
  asm("v_cvt_pk_bf16_f32 %0, %1, %2" : "=v"(r) : "v"(lo), "v"(hi));
  return r;
}

#define GLDS16(g, l) __builtin_amdgcn_global_load_lds( \
    (__attribute__((address_space(1))) void*)(g), \
    (__attribute__((address_space(3))) void*)(l), 16, 0, 0)

// ---------------- prep kernels ----------------

__global__ __launch_bounds__(256) void k_cast_bf16(const float* __restrict__ src,
                                                   unsigned short* __restrict__ dst, int n4) {
  int i = blockIdx.x * 256 + threadIdx.x;
  if (i >= n4) return;
  const float4* s = (const float4*)src;
  float4 v = s[i];
  us4 o = { f2bf(v.x), f2bf(v.y), f2bf(v.z), f2bf(v.w) };
  *(us4*)(dst + (size_t)i * 4) = o;
}

// dst[n*K+k] = bf16(src[k*N+n]); K,N multiples of 64
__global__ __launch_bounds__(256) void k_transpose_bf16(const float* __restrict__ src,
    unsigned short* __restrict__ dst, int K, int N) {
  __shared__ float tile[64][65];
  int k0 = blockIdx.x * 64, n0 = blockIdx.y * 64;
  int t = threadIdx.x;
#pragma unroll
  for (int i = 0; i < 16; ++i) {
    int idx = t + i * 256;
    int r = idx >> 6, c = idx & 63;
    tile[r][c] = src[(size_t)(k0 + r) * N + n0 + c];
  }
  __syncthreads();
#pragma unroll
  for (int i = 0; i < 16; ++i) {
    int idx = t + i * 256;
    int r = idx >> 6, c = idx & 63;
    dst[(size_t)(n0 + r) * K + k0 + c] = f2bf(tile[c][r]);
  }
}

// in-place RoPE on Q (cols 0..2047) and K (cols 2048..2559) of QKV [S][3072]
// Q additionally scaled by log2(e)/sqrt(HD). Uses cos[d+64]==cos[d].
__global__ __launch_bounds__(256) void k_rope(unsigned short* __restrict__ QKV,
    const float* __restrict__ cp, const float* __restrict__ sp) {
  int gid = blockIdx.x * 256 + threadIdx.x;   // S*20*16 total
  int d4 = (gid & 15) * 4;
  int hh = (gid >> 4) % 20;
  int s = gid / 320;
  int col = hh < NH ? hh * HD : DMODEL + (hh - NH) * HD;
  float qs = hh < NH ? 0.12751589341664477f : 1.0f;  // log2e/sqrt(128) for Q heads
  size_t base = (size_t)s * LDQKV + col + d4;
  us4 x1 = *(us4*)(QKV + base);
  us4 x2 = *(us4*)(QKV + base + 64);
  float4 c = *(const float4*)(cp + s * HD + d4);
  float4 sn = *(const float4*)(sp + s * HD + d4);
  us4 o1, o2;
  o1[0] = f2bf((bf2f(x1[0]) * c.x - bf2f(x2[0]) * sn.x) * qs);
  o1[1] = f2bf((bf2f(x1[1]) * c.y - bf2f(x2[1]) * sn.y) * qs);
  o1[2] = f2bf((bf2f(x1[2]) * c.z - bf2f(x2[2]) * sn.z) * qs);
  o1[3] = f2bf((bf2f(x1[3]) * c.w - bf2f(x2[3]) * sn.w) * qs);
  o2[0] = f2bf((bf2f(x2[0]) * c.x + bf2f(x1[0]) * sn.x) * qs);
  o2[1] = f2bf((bf2f(x2[1]) * c.y + bf2f(x1[1]) * sn.y) * qs);
  o2[2] = f2bf((bf2f(x2[2]) * c.z + bf2f(x1[2]) * sn.z) * qs);
  o2[3] = f2bf((bf2f(x2[3]) * c.w + bf2f(x1[3]) * sn.w) * qs);
  *(us4*)(QKV + base) = o1;
  *(us4*)(QKV + base + 64) = o2;
}

// Vt[(kvh*128+d)*S + blk*64 + c] = QKV[blk*64 + pi(c)][2560 + kvh*128 + d]
// pi(c) = (c&3)*16 + (c>>2)  — k-permutation matching the P storage layout.
__global__ __launch_bounds__(256) void k_transpose_v(const unsigned short* __restrict__ QKV,
    unsigned short* __restrict__ Vt) {
  __shared__ unsigned short tile[64][72];
  int s0 = blockIdx.x * 64, c0 = blockIdx.y * 64;
  int t = threadIdx.x;
#pragma unroll
  for (int i = 0; i < 16; ++i) {
    int idx = t + i * 256;
    int r = idx >> 6, c = idx & 63;
    tile[r][c] = QKV[(size_t)(s0 + r) * LDQKV + DMODEL + NKVH * HD + c0 + c];
  }
  __syncthreads();
#pragma unroll
  for (int i = 0; i < 16; ++i) {
    int idx = t + i * 256;
    int r = idx >> 6, c = idx & 63;
    int pc = (c & 3) * 16 + (c >> 2);
    Vt[(size_t)(c0 + r) * S_LEN + s0 + c] = tile[pc][r];
  }
}

// ---------------- GEMM: C[M][N] = A[M][K] * Bt[N][K]^T ----------------

template<int OUTF32>
__global__ __launch_bounds__(256) void k_gemm_bt(
    const unsigned short* __restrict__ A, const unsigned short* __restrict__ Bt,
    void* __restrict__ Cp, int M, int N, int K) {
  __shared__ __attribute__((aligned(16))) unsigned short As[128 * 32];
  __shared__ __attribute__((aligned(16))) unsigned short Bs[128 * 32];
  const int t = threadIdx.x;
  const int wave = t >> 6, lane = t & 63;
  const int lr = lane & 15, lg = lane >> 4;
  const int bm = blockIdx.x * 128, bn = blockIdx.y * 128;
  const int wr = (wave >> 1) * 64, wc = (wave & 1) * 64;
  f32x4 acc[4][4];
#pragma unroll
  for (int i = 0; i < 4; ++i)
#pragma unroll
    for (int j = 0; j < 4; ++j) acc[i][j] = (f32x4){0.f, 0.f, 0.f, 0.f};

  for (int k0 = 0; k0 < K; k0 += 32) {
    __syncthreads();
#pragma unroll
    for (int i = 0; i < 2; ++i) {
      const int cb = (wave * 2 + i) * 64;
      const int c = cb + lane;
      const int row = c >> 2, kc = c & 3;
      const int ksw = (kc ^ (row & 3)) * 8;
      GLDS16(A + (size_t)(bm + row) * K + k0 + ksw, (char*)As + cb * 16);
      GLDS16(Bt + (size_t)(bn + row) * K + k0 + ksw, (char*)Bs + cb * 16);
    }
    asm volatile("s_waitcnt vmcnt(0)" ::: "memory");
    __syncthreads();
    bf16x8 af[4], bfr[4];
#pragma unroll
    for (int mi = 0; mi < 4; ++mi) {
      const int row = wr + mi * 16 + lr;
      af[mi] = *(const bf16x8*)(As + row * 32 + ((lg ^ (lr & 3)) * 8));
    }
#pragma unroll
    for (int ni = 0; ni < 4; ++ni) {
      const int row = wc + ni * 16 + lr;
      bfr[ni] = *(const bf16x8*)(Bs + row * 32 + ((lg ^ (lr & 3)) * 8));
    }
#pragma unroll
    for (int mi = 0; mi < 4; ++mi)
#pragma unroll
      for (int ni = 0; ni < 4; ++ni)
        acc[mi][ni] = __builtin_amdgcn_mfma_f32_16x16x32_bf16(af[mi], bfr[ni], acc[mi][ni], 0, 0, 0);
  }
#pragma unroll
  for (int mi = 0; mi < 4; ++mi)
#pragma unroll
    for (int ni = 0; ni < 4; ++ni)
#pragma unroll
      for (int r = 0; r < 4; ++r) {
        const int m = bm + wr + mi * 16 + lg * 4 + r;
        const int n = bn + wc + ni * 16 + lr;
        if (OUTF32) ((float*)Cp)[(size_t)m * N + n] = acc[mi][ni][r];
        else ((unsigned short*)Cp)[(size_t)m * N + n] = f2bf(acc[mi][ni][r]);
      }
}

// ---------------- fused causal gated attention (v6: 8-wave, KVBLK=128) ----------------
// grid (16, NH), 512 threads. Block bx serves q-super-tiles A=31-bx then B=bx
// (128 rows each); KV tiles are 128x128 (K and V^T), double-buffered.
// 34 tile-iterations per block; 2 barriers per 128 KV cols.

#define STAGE_KV(kt_, buf_) do { \
  const int kv0_ = (kt_) * 128; \
  _Pragma("unroll") \
  for (int i_ = 0; i_ < 4; ++i_) { \
    const int cb_ = (wave * 4 + i_) * 64; \
    const int c_ = cb_ + lane; \
    const int row_ = c_ >> 4, kc_ = c_ & 15; \
    const int sw_ = (kc_ ^ (row_ & 7)) * 8; \
    GLDS16(Kp + (size_t)(kv0_ + row_) * LDQKV + sw_, (char*)Ks[buf_] + cb_ * 16); \
    GLDS16(Vp + (size_t)row_ * S_LEN + kv0_ + sw_, (char*)Vs[buf_] + cb_ * 16); \
  } \
} while (0)

__device__ __forceinline__ void qkt_one(const unsigned short* Kb,
    const bf16x8* qf, f32x4* sc, int lr, int lg) {
  __builtin_amdgcn_s_setprio(1);
#pragma unroll
  for (int cf = 0; cf < 8; ++cf) {
    sc[cf] = (f32x4){0.f, 0.f, 0.f, 0.f};
    const int row = cf * 16 + lr;
#pragma unroll
    for (int ks = 0; ks < 4; ++ks) {
      bf16x8 kb = *(const bf16x8*)(Kb + row * 128 + (((ks * 4 + lg) ^ (lr & 7)) * 8));
      sc[cf] = __builtin_amdgcn_mfma_f32_16x16x32_bf16(qf[ks], kb, sc[cf], 0, 0, 0);
    }
  }
  __builtin_amdgcn_s_setprio(0);
}

template<bool DIAG>
__device__ __forceinline__ void softmax_pv(
    f32x4* sc, const unsigned short* Vb, unsigned short (*PsW)[72],
    const float* g8, int kv0, int qbase,
    f32x4* acc, f32x4& acc_s, float* mrow, int lr, int lg,
    const bf16x8 vb_ones) {
  if (DIAG) {
#pragma unroll
    for (int cf = 0; cf < 8; ++cf) {
      const int kpos = kv0 + cf * 16 + lr;
#pragma unroll
      for (int r = 0; r < 4; ++r)
        sc[cf][r] = (kpos <= qbase + r) ? sc[cf][r] : -3e38f;
    }
  }
  float lmax[4];
#pragma unroll
  for (int r = 0; r < 4; ++r) {
    float a = fmaxf(fmaxf(sc[0][r], sc[1][r]), fmaxf(sc[2][r], sc[3][r]));
    float b = fmaxf(fmaxf(sc[4][r], sc[5][r]), fmaxf(sc[6][r], sc[7][r]));
    lmax[r] = fmaxf(a, b);
  }
  bool need = (lmax[0] > mrow[0] + 11.5416f) | (lmax[1] > mrow[1] + 11.5416f) |
              (lmax[2] > mrow[2] + 11.5416f) | (lmax[3] > mrow[3] + 11.5416f);
  if (__any(need)) {
    float tm[4] = {lmax[0], lmax[1], lmax[2], lmax[3]};
#pragma unroll
    for (int off = 8; off; off >>= 1)
#pragma unroll
      for (int r = 0; r < 4; ++r) tm[r] = fmaxf(tm[r], __shfl_xor(tm[r], off));
#pragma unroll
    for (int r = 0; r < 4; ++r) {
      const float mn = fmaxf(mrow[r], tm[r]);
      const float alpha = __builtin_amdgcn_exp2f(mrow[r] - mn);
      mrow[r] = mn;
#pragma unroll
      for (int j = 0; j < 8; ++j) acc[j][r] *= alpha;
      acc_s[r] *= alpha;
    }
  }
  // two 64-col halves: exp+pack+write P, then PV for that half.
#pragma unroll
  for (int hh = 0; hh < 2; ++hh) {
    const f32x4* s4 = sc + hh * 4;
    const float* g4 = g8 + hh * 4;
#pragma unroll
    for (int r = 0; r < 4; ++r) {
      float p0 = __builtin_amdgcn_exp2f(s4[0][r] - mrow[r]) * g4[0];
      float p1 = __builtin_amdgcn_exp2f(s4[1][r] - mrow[r]) * g4[1];
      float p2 = __builtin_amdgcn_exp2f(s4[2][r] - mrow[r]) * g4[2];
      float p3 = __builtin_amdgcn_exp2f(s4[3][r] - mrow[r]) * g4[3];
      uint2 pk = { cvt_pk_bf16(p0, p1), cvt_pk_bf16(p2, p3) };
      *(uint2*)(&PsW[lg * 4 + r][lr * 4]) = pk;
    }
    asm volatile("s_waitcnt lgkmcnt(0)" ::: "memory");
    __builtin_amdgcn_sched_barrier(0);
    __builtin_amdgcn_s_setprio(1);
#pragma unroll
    for (int ks = 0; ks < 2; ++ks) {
      bf16x8 pa = *(const bf16x8*)(&PsW[lr][ks * 32 + lg * 8]);
#pragma unroll
      for (int j = 0; j < 8; ++j) {
        const int d = j * 16 + lr;
        bf16x8 vb = *(const bf16x8*)(Vb + d * 128 + ((hh * 8 + ((ks * 4 + lg) ^ (lr & 7))) * 8));
        acc[j] = __builtin_amdgcn_mfma_f32_16x16x32_bf16(pa, vb, acc[j], 0, 0, 0);
      }
      acc_s = __builtin_amdgcn_mfma_f32_16x16x32_bf16(pa, vb_ones, acc_s, 0, 0, 0);
    }
    __builtin_amdgcn_s_setprio(0);
  }
}

__global__ __launch_bounds__(512) void k_attn(
    const unsigned short* __restrict__ QKV, const unsigned short* __restrict__ Vt,
    const float* __restrict__ gate, unsigned short* __restrict__ Oattn) {
  __shared__ __attribute__((aligned(16))) unsigned short Ks[2][128 * 128];
  __shared__ __attribute__((aligned(16))) unsigned short Vs[2][128 * 128];
  __shared__ __attribute__((aligned(16))) unsigned short Ps[8][16][72];
  const int h = blockIdx.y, kvh = h >> 2;
  const int bx = blockIdx.x;           // 0..15
  const int t = threadIdx.x, wave = t >> 6, lane = t & 63;
  const int lr = lane & 15, lg = lane >> 4;
  const unsigned short* Qp = QKV + h * HD;
  const unsigned short* Kp = QKV + DMODEL + kvh * HD;
  const unsigned short* Vp = Vt + (size_t)kvh * HD * S_LEN;
  unsigned short (*PsW)[72] = Ps[wave];
  bf16x8 vb_ones;
  {
    const short one = (short)0x3F80, z = 0;
    const short e = (lr == 0) ? one : z;
    vb_ones = (bf16x8){e, e, e, e, e, e, e, e};
  }

  for (int half = 0; half < 2; ++half) {
    const int st = half ? bx : (31 - bx);   // super-tile (128 rows), heavy first
    const int q0 = st * 128;
    const int nt = st + 1;                  // KV tiles (128 wide) 0..nt-1
    const int qbase = q0 + wave * 16 + lg * 4;

    bf16x8 qf[4];
    {
      const size_t qoff = (size_t)(q0 + wave * 16 + lr) * LDQKV;
#pragma unroll
      for (int ks = 0; ks < 4; ++ks)
        qf[ks] = *(const bf16x8*)(Qp + qoff + ks * 32 + lg * 8);
    }
    f32x4 acc[8];
#pragma unroll
    for (int j = 0; j < 8; ++j) acc[j] = (f32x4){0.f, 0.f, 0.f, 0.f};
    f32x4 acc_s = (f32x4){0.f, 0.f, 0.f, 0.f};
    float mrow[4] = {-3e38f, -3e38f, -3e38f, -3e38f};
    f32x4 sc[8];
    float g8[8];

    __builtin_amdgcn_s_barrier();        // protect buf0 from previous half's reads
    STAGE_KV(0, 0);

    int kt = 0;
    for (; kt < nt - 1; ++kt) {
      STAGE_KV(kt + 1, (kt + 1) & 1);
      asm volatile("s_waitcnt vmcnt(8)" ::: "memory");
      __builtin_amdgcn_s_barrier();
#pragma unroll
      for (int cf = 0; cf < 8; ++cf) g8[cf] = gate[kt * 128 + cf * 16 + lr];
      qkt_one(Ks[kt & 1], qf, sc, lr, lg);
      softmax_pv<false>(sc, Vs[kt & 1], PsW, g8, kt * 128, qbase, acc, acc_s, mrow, lr, lg, vb_ones);
      __builtin_amdgcn_s_barrier();
    }
    // diagonal tile (kv0 == q0)
    {
      asm volatile("s_waitcnt vmcnt(0)" ::: "memory");
      __builtin_amdgcn_s_barrier();
#pragma unroll
      for (int cf = 0; cf < 8; ++cf) g8[cf] = gate[kt * 128 + cf * 16 + lr];
      qkt_one(Ks[kt & 1], qf, sc, lr, lg);
      softmax_pv<true>(sc, Vs[kt & 1], PsW, g8, kt * 128, qbase, acc, acc_s, mrow, lr, lg, vb_ones);
    }

    float inv[4];
#pragma unroll
    for (int r = 0; r < 4; ++r)
      inv[r] = 1.0f / __shfl(acc_s[r], lane & 48);
#pragma unroll
    for (int j = 0; j < 8; ++j)
#pragma unroll
      for (int r = 0; r < 4; ++r)
        Oattn[(size_t)(qbase + r) * DMODEL + h * HD + j * 16 + lr] = f2bf(acc[j][r] * inv[r]);
  }
}

// ---------------- launch ----------------

extern "C" void kernel_launch(void* const* d_in, const int* in_sizes, int n_in,
                              void* d_out, int out_size, void* d_ws, size_t ws_size,
                              hipStream_t stream) {
  (void)in_sizes; (void)n_in; (void)out_size; (void)ws_size;
  const float* hid  = (const float*)d_in[0];
  // d_in[1] = attention_mask (pure causal; recomputed inline, never read)
  const float* cosp = (const float*)d_in[2];
  const float* sinp = (const float*)d_in[3];
  const float* gate = (const float*)d_in[4];
  const float* Wq   = (const float*)d_in[5];
  const float* Wk   = (const float*)d_in[6];
  const float* Wv   = (const float*)d_in[7];
  const float* Wo   = (const float*)d_in[8];
  float* out = (float*)d_out;
  char* ws = (char*)d_ws;
  unsigned short* Xb   = (unsigned short*)(ws);                       // 16 MB  [4096][2048] bf16
  unsigned short* Wt   = (unsigned short*)(ws + (size_t)16777216);    // 12 MB  [3072][2048] bf16 (Wq|Wk|Wv)^T
  unsigned short* Wot  = (unsigned short*)(ws + (size_t)29360128);    //  8 MB  [2048][2048] bf16 Wo^T
  unsigned short* QKV  = (unsigned short*)(ws + (size_t)37748736);    // 24 MB  [4096][3072] bf16
  unsigned short* Oatt = (unsigned short*)(ws + (size_t)62914560);    // 16 MB  [4096][2048] bf16
  unsigned short* Vt   = (unsigned short*)(ws + (size_t)79691776);    //  4 MB  [4][128][4096] bf16

  k_cast_bf16<<<8192, 256, 0, stream>>>(hid, Xb, 2097152);
  k_transpose_bf16<<<dim3(32, 32), 256, 0, stream>>>(Wq, Wt, 2048, 2048);
  k_transpose_bf16<<<dim3(32, 8), 256, 0, stream>>>(Wk, Wt + (size_t)2048 * 2048, 2048, 512);
  k_transpose_bf16<<<dim3(32, 8), 256, 0, stream>>>(Wv, Wt + (size_t)2560 * 2048, 2048, 512);
  k_transpose_bf16<<<dim3(32, 32), 256, 0, stream>>>(Wo, Wot, 2048, 2048);
  k_gemm_bt<0><<<dim3(32, 24), 256, 0, stream>>>(Xb, Wt, QKV, 4096, 3072, 2048);
  k_rope<<<5120, 256, 0, stream>>>(QKV, cosp, sinp);
  k_transpose_v<<<dim3(64, 8), 256, 0, stream>>>(QKV, Vt);
  k_attn<<<dim3(16, 16), 512, 0, stream>>>(QKV, Vt, gate, Oatt);
  k_gemm_bt<1><<<dim3(32, 16), 256, 0, stream>>>(Oatt, Wot, out, 4096, 2048, 2048);
}